// Round 1
// baseline (2816.211 us; speedup 1.0000x reference)
//
#include <hip/hip_runtime.h>

#define DEV static __device__ __forceinline__

typedef short bf16x8 __attribute__((ext_vector_type(8)));
typedef float f32x4 __attribute__((ext_vector_type(4)));
typedef unsigned short u16;
typedef unsigned int u32;

#define SS 1024
#define DD 1024
#define HH 16
#define LL 8
#define FF 4096
#define VV 32000
#define NROW 2048  // B*S

// ---- static device scratch (avoids depending on ws_size) ----
__device__ float g_x[NROW * DD];     // residual stream, f32
__device__ u16   g_h[NROW * DD];     // LN output, bf16
__device__ u16   g_q[NROW * DD];     // [B][H][S][DH]
__device__ u16   g_k[NROW * DD];     // [B][H][S][DH]
__device__ u16   g_vT[NROW * DD];    // [B][H][DH][S]
__device__ u16   g_o[NROW * DD];     // [B][S][D]
__device__ u16   g_fc1[NROW * FF];   // [rows][F]
__device__ u16   g_wt[FF * DD];      // transposed bf16 weight slice [N][K]
__device__ u16   g_emb[VV * DD];     // tok_emb bf16 [V][D]

struct __align__(8) us4 { u16 a, b, c, d; };

DEV u16 f2bf(float f) {
  u32 u = __builtin_bit_cast(u32, f);
  u32 r = u + 0x7FFFu + ((u >> 16) & 1u);
  return (u16)(r >> 16);
}

DEV void gload16(const void* g, void* l) {
  __builtin_amdgcn_global_load_lds((const __attribute__((address_space(1))) u32*)g,
                                   (__attribute__((address_space(3))) u32*)l, 16, 0, 0);
}

// ---- tok_emb f32 -> bf16 ----
__global__ __launch_bounds__(256) void k_cvt(const float* __restrict__ te) {
  const int i = (blockIdx.x * 256 + threadIdx.x) << 2;
  float4 v = *(const float4*)&te[i];
  us4 pk{f2bf(v.x), f2bf(v.y), f2bf(v.z), f2bf(v.w)};
  *(us4*)&g_emb[i] = pk;
}

// ---- embedding: x = tok_emb[ids] + pos_emb ----
__global__ __launch_bounds__(256) void k_embed(const int* __restrict__ ids,
                                               const float* __restrict__ te,
                                               const float* __restrict__ pe) {
  const int row = blockIdx.x;
  const int s = row & (SS - 1);
  const int id = ids[row];
  const int d = threadIdx.x << 2;
  float4 a = *(const float4*)&te[id * DD + d];
  float4 p = *(const float4*)&pe[s * DD + d];
  a.x += p.x; a.y += p.y; a.z += p.z; a.w += p.w;
  *(float4*)&g_x[row * DD + d] = a;
}

// ---- layernorm g_x -> g_h (bf16), 1 wave per row ----
__global__ __launch_bounds__(256) void k_ln(const float* __restrict__ w,
                                            const float* __restrict__ b) {
  const int wid = threadIdx.x >> 6, l = threadIdx.x & 63;
  const int row = (blockIdx.x << 2) + wid;
  const float* xr = g_x + row * DD;
  float4 v[4];
  float s = 0.f, ss = 0.f;
#pragma unroll
  for (int i = 0; i < 4; ++i) {
    v[i] = *(const float4*)&xr[(l << 2) + (i << 8)];
    s += v[i].x + v[i].y + v[i].z + v[i].w;
    ss += v[i].x * v[i].x + v[i].y * v[i].y + v[i].z * v[i].z + v[i].w * v[i].w;
  }
#pragma unroll
  for (int off = 1; off < 64; off <<= 1) {
    s += __shfl_xor(s, off);
    ss += __shfl_xor(ss, off);
  }
  const float mu = s * (1.f / DD);
  const float rs = rsqrtf(ss * (1.f / DD) - mu * mu + 1e-5f);
#pragma unroll
  for (int i = 0; i < 4; ++i) {
    const int d = (l << 2) + (i << 8);
    us4 pk{f2bf((v[i].x - mu) * rs * w[d] + b[d]),
           f2bf((v[i].y - mu) * rs * w[d + 1] + b[d + 1]),
           f2bf((v[i].z - mu) * rs * w[d + 2] + b[d + 2]),
           f2bf((v[i].w - mu) * rs * w[d + 3] + b[d + 3])};
    *(us4*)&g_h[row * DD + d] = pk;
  }
}

// ---- transpose+convert weight slice: W f32 [K][N] -> g_wt bf16 [N][K] ----
__global__ __launch_bounds__(256) void k_trans(const float* __restrict__ W, int K, int N) {
  __shared__ u16 tile[32][33];
  const int n0 = blockIdx.x << 5, k0 = blockIdx.y << 5;
  const int tx = threadIdx.x, ty = threadIdx.y;
#pragma unroll
  for (int i = 0; i < 4; ++i)
    tile[ty + i * 8][tx] = f2bf(W[(k0 + ty + i * 8) * N + n0 + tx]);
  __syncthreads();
#pragma unroll
  for (int i = 0; i < 4; ++i)
    g_wt[(n0 + ty + i * 8) * K + k0 + tx] = tile[tx][ty + i * 8];
}

// ---- GEMM: C[M=2048][N] = A[M][K]bf16 @ Bt[N][K]bf16^T, mode-specific epilogue ----
// MODE 0: QKV (A=g_h, Bt=g_wt, N=3072) -> g_q/g_k/g_vT (+bias)
// MODE 1: attn proj (A=g_o, N=1024)    -> g_x += acc+bias
// MODE 2: FC1 (A=g_h, N=4096)         -> g_fc1 = gelu(acc+bias)
// MODE 3: FC2 (A=g_fc1, N=1024,K=4096)-> g_x += acc+bias
// MODE 4: logits (A=g_h, Bt=g_emb, N=32000) -> fout = acc
template <int MODE>
__global__ __launch_bounds__(256) void k_gemm(const float* __restrict__ bias,
                                              float* __restrict__ fout) {
  constexpr int N = (MODE == 0) ? 3072 : (MODE == 2) ? 4096 : (MODE == 4) ? 32000 : 1024;
  constexpr int K = (MODE == 3) ? 4096 : 1024;
  const u16* __restrict__ A = (MODE == 1) ? g_o : (MODE == 3) ? g_fc1 : g_h;
  const u16* __restrict__ Bt = (MODE == 4) ? g_emb : g_wt;

  __shared__ u16 As[128 * 64];
  __shared__ u16 Bs[128 * 64];
  const int t = threadIdx.x;
  const int l = t & 63, wid = t >> 6;
  const int l15 = l & 15, l4 = l >> 4;
  const int wr = (wid >> 1) << 6, wc = (wid & 1) << 6;
  const int m0 = blockIdx.y << 7, n0 = blockIdx.x << 7;

  const int srow = t >> 3, scol = (t & 7) << 3;
  const u16* ga = A + (m0 + srow) * K + scol;
  const u16* gb = Bt + (n0 + srow) * K + scol;
  u16* lA = &As[t << 3];
  u16* lB = &Bs[t << 3];

  f32x4 acc[4][4] = {};

  for (int kt = 0; kt < K; kt += 64) {
    __syncthreads();
#pragma unroll
    for (int i = 0; i < 4; ++i) {
      gload16(ga + i * 32 * K + kt, lA + i * 2048);
      gload16(gb + i * 32 * K + kt, lB + i * 2048);
    }
    __syncthreads();
#pragma unroll
    for (int kk = 0; kk < 2; ++kk) {
      const int ko = (kk << 5) + (l4 << 3);
      bf16x8 af[4], bfr[4];
#pragma unroll
      for (int m = 0; m < 4; ++m) af[m] = *(const bf16x8*)&As[((wr + (m << 4) + l15) << 6) + ko];
#pragma unroll
      for (int n = 0; n < 4; ++n) bfr[n] = *(const bf16x8*)&Bs[((wc + (n << 4) + l15) << 6) + ko];
#pragma unroll
      for (int m = 0; m < 4; ++m)
#pragma unroll
        for (int n = 0; n < 4; ++n)
          acc[m][n] = __builtin_amdgcn_mfma_f32_16x16x32_bf16(af[m], bfr[n], acc[m][n], 0, 0, 0);
    }
  }

#pragma unroll
  for (int m = 0; m < 4; ++m) {
#pragma unroll
    for (int n = 0; n < 4; ++n) {
      const int gc = n0 + wc + (n << 4) + l15;
      float bv = 0.f;
      if constexpr (MODE != 4) bv = bias[gc];
#pragma unroll
      for (int r = 0; r < 4; ++r) {
        const int gr = m0 + wr + (m << 4) + (l4 << 2) + r;
        const float v = acc[m][n][r] + bv;
        if constexpr (MODE == 0) {
          const int which = gc >> 10, within = gc & 1023;
          const int head = within >> 6, dh = within & 63;
          const int bh = ((gr >> 10) << 4) + head, sr = gr & 1023;
          const u16 bits = f2bf(v);
          if (which == 0)      g_q[(((bh << 10) + sr) << 6) + dh] = bits;
          else if (which == 1) g_k[(((bh << 10) + sr) << 6) + dh] = bits;
          else                 g_vT[(((bh << 6) + dh) << 10) + sr] = bits;
        } else if constexpr (MODE == 1 || MODE == 3) {
          g_x[gr * DD + gc] += v;
        } else if constexpr (MODE == 2) {
          g_fc1[gr * FF + gc] = f2bf(0.5f * v * (1.f + erff(v * 0.70710678118f)));
        } else {
          fout[gr * VV + gc] = v;
        }
      }
    }
  }
}

// ---- flash attention: 1 block = (b,h) x 128 q-rows; K/V tiles of 64 ----
__global__ __launch_bounds__(256) void k_attn() {
  __shared__ u16 Qs[128 * 64];
  __shared__ u16 Ks[64 * 64];
  __shared__ u16 Vs[64 * 64];   // [dh][spos]
  __shared__ u16 Ps[4][32 * 64];
  const int t = threadIdx.x, l = t & 63, wid = t >> 6;
  const int l15 = l & 15, l4 = l >> 4;
  const int bh = blockIdx.y, qb = blockIdx.x;
  const int q0 = qb << 7;
  const int srow = t >> 3, scol = (t & 7) << 3;

  const u16* qg = g_q + (((bh << 10) + q0) << 6);
  const u16* kg = g_k + ((bh << 10) << 6);
  const u16* vg = g_vT + ((bh << 6) << 10);

#pragma unroll
  for (int i = 0; i < 4; ++i)
    gload16(qg + ((i * 32 + srow) << 6) + scol, &Qs[((i * 32 + srow) << 6) + scol]);

  f32x4 of[2][4] = {};
  float mrow[2][4], lsum[2][4];
#pragma unroll
  for (int m = 0; m < 2; ++m)
#pragma unroll
    for (int r = 0; r < 4; ++r) { mrow[m][r] = -1e30f; lsum[m][r] = 0.f; }

  bf16x8 qf[2][2];

  const int nt = (qb << 1) + 2;
  for (int kt = 0; kt < nt; ++kt) {
    const int s0 = kt << 6;
    __syncthreads();
#pragma unroll
    for (int i = 0; i < 2; ++i) {
      gload16(kg + ((s0 + i * 32 + srow) << 6) + scol, &Ks[((i * 32 + srow) << 6) + scol]);
      gload16(vg + ((i * 32 + srow) << 10) + s0 + scol, &Vs[((i * 32 + srow) << 6) + scol]);
    }
    __syncthreads();
    if (kt == 0) {
#pragma unroll
      for (int m = 0; m < 2; ++m)
#pragma unroll
        for (int kk = 0; kk < 2; ++kk)
          qf[m][kk] = *(const bf16x8*)&Qs[(((wid << 5) + (m << 4) + l15) << 6) + (kk << 5) + (l4 << 3)];
    }
    f32x4 sa[2][4] = {};
#pragma unroll
    for (int kk = 0; kk < 2; ++kk) {
      bf16x8 kf[4];
#pragma unroll
      for (int n = 0; n < 4; ++n)
        kf[n] = *(const bf16x8*)&Ks[(((n << 4) + l15) << 6) + (kk << 5) + (l4 << 3)];
#pragma unroll
      for (int m = 0; m < 2; ++m)
#pragma unroll
        for (int n = 0; n < 4; ++n)
          sa[m][n] = __builtin_amdgcn_mfma_f32_16x16x32_bf16(qf[m][kk], kf[n], sa[m][n], 0, 0, 0);
    }
    const bool maskt = (s0 >= q0);
    float pv[2][4][4];
#pragma unroll
    for (int m = 0; m < 2; ++m) {
      float rm[4] = {-1e30f, -1e30f, -1e30f, -1e30f};
#pragma unroll
      for (int n = 0; n < 4; ++n)
#pragma unroll
        for (int r = 0; r < 4; ++r) {
          float v = sa[m][n][r] * 0.125f;
          if (maskt) {
            const int col = s0 + (n << 4) + l15;
            const int row = q0 + (wid << 5) + (m << 4) + (l4 << 2) + r;
            if (col > row) v = -1e30f;
          }
          pv[m][n][r] = v;
          rm[r] = fmaxf(rm[r], v);
        }
#pragma unroll
      for (int r = 0; r < 4; ++r) {
#pragma unroll
        for (int off = 1; off < 16; off <<= 1) rm[r] = fmaxf(rm[r], __shfl_xor(rm[r], off));
        const float nm = fmaxf(mrow[m][r], rm[r]);
        const float alpha = __expf(mrow[m][r] - nm);
        mrow[m][r] = nm;
        float ps = 0.f;
#pragma unroll
        for (int n = 0; n < 4; ++n) { pv[m][n][r] = __expf(pv[m][n][r] - nm); ps += pv[m][n][r]; }
#pragma unroll
        for (int off = 1; off < 16; off <<= 1) ps += __shfl_xor(ps, off);
        lsum[m][r] = lsum[m][r] * alpha + ps;
#pragma unroll
        for (int n = 0; n < 4; ++n) of[m][n][r] *= alpha;
      }
#pragma unroll
      for (int n = 0; n < 4; ++n)
#pragma unroll
        for (int r = 0; r < 4; ++r)
          Ps[wid][(((m << 4) + (l4 << 2) + r) << 6) + (n << 4) + l15] = f2bf(pv[m][n][r]);
    }
#pragma unroll
    for (int kk = 0; kk < 2; ++kk) {
      bf16x8 pa[2], vb[4];
#pragma unroll
      for (int m = 0; m < 2; ++m)
        pa[m] = *(const bf16x8*)&Ps[wid][(((m << 4) + l15) << 6) + (kk << 5) + (l4 << 3)];
#pragma unroll
      for (int n = 0; n < 4; ++n)
        vb[n] = *(const bf16x8*)&Vs[(((n << 4) + l15) << 6) + (kk << 5) + (l4 << 3)];
#pragma unroll
      for (int m = 0; m < 2; ++m)
#pragma unroll
        for (int n = 0; n < 4; ++n)
          of[m][n] = __builtin_amdgcn_mfma_f32_16x16x32_bf16(pa[m], vb[n], of[m][n], 0, 0, 0);
    }
  }
  const int b = bh >> 4, h = bh & 15;
#pragma unroll
  for (int m = 0; m < 2; ++m)
#pragma unroll
    for (int r = 0; r < 4; ++r) {
      const float inv = 1.f / lsum[m][r];
      const int s = q0 + (wid << 5) + (m << 4) + (l4 << 2) + r;
#pragma unroll
      for (int n = 0; n < 4; ++n)
        g_o[((b << 10) + s) * DD + (h << 6) + (n << 4) + l15] = f2bf(of[m][n][r] * inv);
    }
}

extern "C" void kernel_launch(void* const* d_in, const int* in_sizes, int n_in,
                              void* d_out, int out_size, void* d_ws, size_t ws_size,
                              hipStream_t stream) {
  (void)in_sizes; (void)n_in; (void)out_size; (void)d_ws; (void)ws_size;
  const int*   ids  = (const int*)d_in[0];
  const float* tok  = (const float*)d_in[1];
  const float* pos  = (const float*)d_in[2];
  const float* ln1w = (const float*)d_in[3];
  const float* ln1b = (const float*)d_in[4];
  const float* qkvw = (const float*)d_in[5];
  const float* qkvb = (const float*)d_in[6];
  const float* outw = (const float*)d_in[7];
  const float* outb = (const float*)d_in[8];
  const float* ln2w = (const float*)d_in[9];
  const float* ln2b = (const float*)d_in[10];
  const float* fc1w = (const float*)d_in[11];
  const float* fc1b = (const float*)d_in[12];
  const float* fc2w = (const float*)d_in[13];
  const float* fc2b = (const float*)d_in[14];
  const float* lnfw = (const float*)d_in[15];
  const float* lnfb = (const float*)d_in[16];
  float* out = (float*)d_out;

  const dim3 b256(256), bt(32, 8);

  k_cvt<<<VV * DD / 1024, b256, 0, stream>>>(tok);
  k_embed<<<NROW, b256, 0, stream>>>(ids, tok, pos);

  for (int l = 0; l < LL; ++l) {
    k_ln<<<NROW / 4, b256, 0, stream>>>(ln1w + l * DD, ln1b + l * DD);
    k_trans<<<dim3(3 * DD / 32, DD / 32), bt, 0, stream>>>(qkvw + (size_t)l * DD * 3 * DD, DD, 3 * DD);
    k_gemm<0><<<dim3(24, 16), b256, 0, stream>>>(qkvb + l * 3 * DD, nullptr);
    k_attn<<<dim3(8, 32), b256, 0, stream>>>();
    k_trans<<<dim3(DD / 32, DD / 32), bt, 0, stream>>>(outw + (size_t)l * DD * DD, DD, DD);
    k_gemm<1><<<dim3(8, 16), b256, 0, stream>>>(outb + l * DD, nullptr);
    k_ln<<<NROW / 4, b256, 0, stream>>>(ln2w + l * DD, ln2b + l * DD);
    k_trans<<<dim3(FF / 32, DD / 32), bt, 0, stream>>>(fc1w + (size_t)l * DD * FF, DD, FF);
    k_gemm<2><<<dim3(32, 16), b256, 0, stream>>>(fc1b + l * FF, nullptr);
    k_trans<<<dim3(DD / 32, FF / 32), bt, 0, stream>>>(fc2w + (size_t)l * FF * DD, FF, DD);
    k_gemm<3><<<dim3(8, 16), b256, 0, stream>>>(fc2b + l * DD, nullptr);
  }
  k_ln<<<NROW / 4, b256, 0, stream>>>(lnfw, lnfb);
  k_gemm<4><<<dim3(250, 16), b256, 0, stream>>>(nullptr, out);
}